// Round 3
// baseline (1144.414 us; speedup 1.0000x reference)
//
#include <hip/hip_runtime.h>
#include <math.h>

#define F 512
#define H 16
#define C 40
#define BW 128          // nodes per bucket (dstloc fits in 7 bits)
#define BSH 7           // log2(BW)
#define NB_MAX 1024     // max buckets supported (N <= 131072)
#define CHUNK 8192      // edges per multisplit block
#define SRC_BITS 17     // src < 2^17 (N = 100000)
#define SRC_MASK 0x1FFFF

// ---------- multisplit pass A: global bucket histogram ----------
__global__ void k_bhist(const int* __restrict__ dst, int* __restrict__ gbh,
                        int E, int NB) {
    __shared__ int hist[NB_MAX];
    for (int i = threadIdx.x; i < NB; i += 256) hist[i] = 0;
    __syncthreads();
    int c0 = blockIdx.x * CHUNK;
    int end = min(c0 + CHUNK, E);
    for (int i = c0 + threadIdx.x; i < end; i += 256)
        atomicAdd(&hist[dst[i] >> BSH], 1);
    __syncthreads();
    for (int i = threadIdx.x; i < NB; i += 256)
        if (hist[i]) atomicAdd(&gbh[i], hist[i]);
}

// ---------- multisplit pass B: 1-block exclusive scan -> brow, bcur ----------
__global__ void k_bscan(const int* __restrict__ gbh, int* __restrict__ brow,
                        int* __restrict__ bcur, int NB, int E) {
    __shared__ int s[1024];
    int t = threadIdx.x;
    int v = (t < NB) ? gbh[t] : 0;
    s[t] = v;
    __syncthreads();
    for (int off = 1; off < 1024; off <<= 1) {
        int add = (t >= off) ? s[t - off] : 0;
        __syncthreads();
        s[t] += add;
        __syncthreads();
    }
    if (t < NB) { int excl = s[t] - v; brow[t] = excl; bcur[t] = excl; }
    if (t == 0) brow[NB] = E;
}

// ---------- multisplit pass C: chunk-local ranked scatter (coalesced runs) ----------
__global__ void k_bscatter(const int* __restrict__ src, const int* __restrict__ dst,
                           int* __restrict__ bcur, int* __restrict__ ebuf,
                           int E, int NB) {
    __shared__ int lhist[NB_MAX];
    __shared__ int lbase[NB_MAX];
    __shared__ int lcur[NB_MAX];
    int c0 = blockIdx.x * CHUNK;
    int end = min(c0 + CHUNK, E);
    for (int i = threadIdx.x; i < NB; i += 256) lhist[i] = 0;
    __syncthreads();
    for (int i = c0 + threadIdx.x; i < end; i += 256)
        atomicAdd(&lhist[dst[i] >> BSH], 1);
    __syncthreads();
    for (int i = threadIdx.x; i < NB; i += 256) {
        int h = lhist[i];
        lbase[i] = h ? atomicAdd(&bcur[i], h) : 0;
        lcur[i] = 0;
    }
    __syncthreads();
    for (int i = c0 + threadIdx.x; i < end; i += 256) {
        int d = dst[i], sv = src[i];
        int b = d >> BSH;
        int r = atomicAdd(&lcur[b], 1);
        ebuf[lbase[b] + r] = ((d & (BW - 1)) << SRC_BITS) | sv;
    }
}

// ---------- degree -> dinv, per-bucket LDS histogram (no global atomics) ----------
__global__ void k_deg(const int* __restrict__ ebuf, const int* __restrict__ brow,
                      float* __restrict__ dinv, int N) {
    __shared__ int cnt[BW];
    int b = blockIdx.x;
    if (threadIdx.x < BW) cnt[threadIdx.x] = 0;
    __syncthreads();
    int beg = brow[b], end = brow[b + 1];
    for (int i = beg + threadIdx.x; i < end; i += 256)
        atomicAdd(&cnt[ebuf[i] >> SRC_BITS], 1);
    __syncthreads();
    if (threadIdx.x < BW) {
        int n = b * BW + threadIdx.x;
        if (n < N) dinv[n] = rsqrtf((float)(cnt[threadIdx.x] + 1));  // +1 self loop
    }
}

// ---------- layer 1 GEMM: h0s[v] = (x[v] @ W1) * dinv[v] ----------
__global__ void k_gemm1(const float* __restrict__ x, const float* __restrict__ W1,
                        const float* __restrict__ dinv, float* __restrict__ h0s, int N) {
    int v = blockIdx.x * 256 + threadIdx.x;
    if (v >= N) return;
    const float4* xr = (const float4*)(x + (size_t)v * F);
    float acc[H];
    #pragma unroll
    for (int j = 0; j < H; j++) acc[j] = 0.f;
    for (int k4 = 0; k4 < F / 4; k4++) {
        float4 xv = xr[k4];
        const float* w = W1 + k4 * 4 * H;   // wave-uniform -> scalar loads
        #pragma unroll
        for (int j = 0; j < H; j++) acc[j] = fmaf(xv.x, w[j], acc[j]);
        #pragma unroll
        for (int j = 0; j < H; j++) acc[j] = fmaf(xv.y, w[H + j], acc[j]);
        #pragma unroll
        for (int j = 0; j < H; j++) acc[j] = fmaf(xv.z, w[2 * H + j], acc[j]);
        #pragma unroll
        for (int j = 0; j < H; j++) acc[j] = fmaf(xv.w, w[3 * H + j], acc[j]);
    }
    float dv = dinv[v];
    float4* o4 = (float4*)(h0s + (size_t)v * H);
    o4[0] = make_float4(acc[0] * dv, acc[1] * dv, acc[2] * dv, acc[3] * dv);
    o4[1] = make_float4(acc[4] * dv, acc[5] * dv, acc[6] * dv, acc[7] * dv);
    o4[2] = make_float4(acc[8] * dv, acc[9] * dv, acc[10] * dv, acc[11] * dv);
    o4[3] = make_float4(acc[12] * dv, acc[13] * dv, acc[14] * dv, acc[15] * dv);
}

// ---------- bucketed aggregation: one block per bucket, LDS f32 accumulator ----------
// relu_mode=1: out = relu(dinv*(acc+self) + b1[j]) * dinv   (layer-1, pre-scaled)
// relu_mode=0: out = dinv*(acc+self)                        (layer-2, pre-W2)
__global__ void k_agg(const float* __restrict__ hs, const int* __restrict__ ebuf,
                      const int* __restrict__ brow, const float* __restrict__ dinv,
                      const float* __restrict__ b1, float* __restrict__ out,
                      int N, int relu_mode) {
    __shared__ float acc[BW * H];   // 8 KB
    int b = blockIdx.x;
    for (int i = threadIdx.x; i < BW * H; i += 256) acc[i] = 0.f;
    __syncthreads();
    int beg = brow[b], end = brow[b + 1];
    int g = threadIdx.x >> 4, j = threadIdx.x & 15;   // 16 groups x 16 lanes
    for (int base = beg; base < end; base += 64) {
        int w[4];
        float v[4];
        #pragma unroll
        for (int u = 0; u < 4; u++) {
            int e = base + g + (u << 4);
            w[u] = (e < end) ? ebuf[e] : -1;
        }
        #pragma unroll
        for (int u = 0; u < 4; u++)
            if (w[u] >= 0) v[u] = hs[(size_t)(w[u] & SRC_MASK) * H + j];
        #pragma unroll
        for (int u = 0; u < 4; u++)
            if (w[u] >= 0) atomicAdd(&acc[((w[u] >> SRC_BITS) << 4) | j], v[u]);
    }
    __syncthreads();
    // epilogue: add self-loop term, scale, write
    for (int i = threadIdx.x; i < BW * H; i += 256) {
        int n = b * BW + (i >> 4);
        if (n >= N) break;
        int jj = i & 15;
        float val = acc[i] + hs[(size_t)n * H + jj];
        float dv = dinv[n];
        float r;
        if (relu_mode) r = fmaxf(fmaf(dv, val, b1[jj]), 0.f) * dv;
        else           r = dv * val;
        out[(size_t)n * H + jj] = r;
    }
}

// ---------- epilogue: h2 = g2 @ W2 + b2 ; softmax ; one wave per node ----------
__global__ void k_out(const float* __restrict__ g2, const float* __restrict__ W2,
                      const float* __restrict__ b2, float* __restrict__ dout, int N) {
    int t = blockIdx.x * 256 + threadIdx.x;
    int n = t >> 6, lane = t & 63;
    if (n >= N) return;
    const float* g = g2 + (size_t)n * H;
    float acc = 0.f;
    #pragma unroll
    for (int k = 0; k < H; k++) {
        float w = (lane < C) ? W2[k * C + lane] : 0.f;
        acc = fmaf(g[k], w, acc);
    }
    float h2 = (lane < C) ? acc + b2[lane] : -INFINITY;
    float m = h2;
    #pragma unroll
    for (int off = 32; off; off >>= 1) m = fmaxf(m, __shfl_xor(m, off, 64));
    float ex = (lane < C) ? __expf(h2 - m) : 0.f;
    float s = ex;
    #pragma unroll
    for (int off = 32; off; off >>= 1) s += __shfl_xor(s, off, 64);
    if (lane < C) {
        float inv = 1.f / s;
        dout[(size_t)n * C + lane] = ex * inv;                       // output 0: softmax
        dout[(size_t)N * C + (size_t)n * C + lane] = h2;             // output 1: logits
    }
}

extern "C" void kernel_launch(void* const* d_in, const int* in_sizes, int n_in,
                              void* d_out, int out_size, void* d_ws, size_t ws_size,
                              hipStream_t stream) {
    const float* x  = (const float*)d_in[0];
    const int*   ei = (const int*)d_in[1];
    const float* W1 = (const float*)d_in[3];
    const float* b1 = (const float*)d_in[4];
    const float* W2 = (const float*)d_in[5];
    const float* b2 = (const float*)d_in[6];
    float* out = (float*)d_out;

    int N = in_sizes[0] / F;       // 100000
    int E = in_sizes[1] / 2;       // 3200000
    const int* src = ei;
    const int* dst = ei + E;
    int NB = (N + BW - 1) / BW;    // 782 (<= NB_MAX)

    // workspace layout (element offsets, padded to 16B alignment)
    float* ws = (float*)d_ws;
    size_t o = 0;
    int* gbh  = (int*)(ws + o); o += (size_t)NB_MAX;
    int* brow = (int*)(ws + o); o += (size_t)NB_MAX + 4;
    int* bcur = (int*)(ws + o); o += (size_t)NB_MAX;
    int* ebuf = (int*)(ws + o); o += (size_t)E;
    float* dinv = ws + o;       o += (size_t)N;
    float* h0s  = ws + o;       o += (size_t)N * H;
    float* h1s  = ws + o;       o += (size_t)N * H;
    float* g2   = ws + o;       o += (size_t)N * H;

    int nb  = (N + 255) / 256;
    int nch = (E + CHUNK - 1) / CHUNK;   // 391

    hipMemsetAsync(gbh, 0, (size_t)NB_MAX * sizeof(int), stream);
    k_bhist   <<<nch, 256, 0, stream>>>(dst, gbh, E, NB);
    k_bscan   <<<1, 1024, 0, stream>>>(gbh, brow, bcur, NB, E);
    k_bscatter<<<nch, 256, 0, stream>>>(src, dst, bcur, ebuf, E, NB);
    k_deg     <<<NB, 256, 0, stream>>>(ebuf, brow, dinv, N);
    k_gemm1   <<<nb, 256, 0, stream>>>(x, W1, dinv, h0s, N);
    k_agg     <<<NB, 256, 0, stream>>>(h0s, ebuf, brow, dinv, b1, h1s, N, 1);
    k_agg     <<<NB, 256, 0, stream>>>(h1s, ebuf, brow, dinv, b1, g2, N, 0);
    k_out     <<<(N * 64 + 255) / 256, 256, 0, stream>>>(g2, W2, b2, out, N);
}

// Round 4
// 630.293 us; speedup vs baseline: 1.8157x; 1.8157x over previous
//
#include <hip/hip_runtime.h>
#include <math.h>

#define F 512
#define H 16
#define C 40
#define BW 128          // nodes per bucket (dstloc fits in 7 bits)
#define BSH 7           // log2(BW)
#define NB_MAX 1024     // max buckets supported (N <= 131072)
#define CHUNK 4096      // edges per multisplit block
#define SRC_BITS 17     // src < 2^17 (N = 100000)
#define SRC_MASK 0x1FFFF
#define SORT_CAP 8192   // max edges per bucket stageable in LDS (mean 4096, sd 64)

// ---------- multisplit pass A: global bucket histogram ----------
__global__ void k_bhist(const int* __restrict__ dst, int* __restrict__ gbh,
                        int E, int NB) {
    __shared__ int hist[NB_MAX];
    for (int i = threadIdx.x; i < NB; i += 256) hist[i] = 0;
    __syncthreads();
    int c0 = blockIdx.x * CHUNK;
    int end = min(c0 + CHUNK, E);
    for (int i = c0 + threadIdx.x; i < end; i += 256)
        atomicAdd(&hist[dst[i] >> BSH], 1);
    __syncthreads();
    for (int i = threadIdx.x; i < NB; i += 256)
        if (hist[i]) atomicAdd(&gbh[i], hist[i]);
}

// ---------- multisplit pass B: 1-block exclusive scan -> brow, bcur ----------
__global__ void k_bscan(const int* __restrict__ gbh, int* __restrict__ brow,
                        int* __restrict__ bcur, int* __restrict__ rowptr,
                        int NB, int N, int E) {
    __shared__ int s[1024];
    int t = threadIdx.x;
    int v = (t < NB) ? gbh[t] : 0;
    s[t] = v;
    __syncthreads();
    for (int off = 1; off < 1024; off <<= 1) {
        int add = (t >= off) ? s[t - off] : 0;
        __syncthreads();
        s[t] += add;
        __syncthreads();
    }
    if (t < NB) { int excl = s[t] - v; brow[t] = excl; bcur[t] = excl; }
    if (t == 0) { brow[NB] = E; rowptr[N] = E; }
}

// ---------- multisplit pass C: chunk-local ranked scatter (coalesced runs) ----------
__global__ void k_bscatter(const int* __restrict__ src, const int* __restrict__ dst,
                           int* __restrict__ bcur, int* __restrict__ ebuf,
                           int E, int NB) {
    __shared__ int lhist[NB_MAX];
    __shared__ int lbase[NB_MAX];
    __shared__ int lcur[NB_MAX];
    int c0 = blockIdx.x * CHUNK;
    int end = min(c0 + CHUNK, E);
    for (int i = threadIdx.x; i < NB; i += 256) lhist[i] = 0;
    __syncthreads();
    for (int i = c0 + threadIdx.x; i < end; i += 256)
        atomicAdd(&lhist[dst[i] >> BSH], 1);
    __syncthreads();
    for (int i = threadIdx.x; i < NB; i += 256) {
        int h = lhist[i];
        lbase[i] = h ? atomicAdd(&bcur[i], h) : 0;
        lcur[i] = 0;
    }
    __syncthreads();
    for (int i = c0 + threadIdx.x; i < end; i += 256) {
        int d = dst[i], sv = src[i];
        int b = d >> BSH;
        int r = atomicAdd(&lcur[b], 1);
        ebuf[lbase[b] + r] = ((d & (BW - 1)) << SRC_BITS) | sv;
    }
}

// ---------- per-bucket LDS counting sort: ebuf -> dst-sorted (in place), rowptr, dinv ----------
__global__ void k_sortb(int* __restrict__ ebuf, const int* __restrict__ brow,
                        int* __restrict__ rowptr, float* __restrict__ dinv, int N) {
    __shared__ int buf[SORT_CAP];        // 32 KB
    __shared__ int hist[BW];
    __shared__ int off[BW];
    __shared__ int cur[BW];
    int b = blockIdx.x;
    int beg = brow[b], end = brow[b + 1];
    int len = end - beg;
    if (len > SORT_CAP) len = SORT_CAP;  // statistically impossible (mean 4096, sd 64)
    int tid = threadIdx.x;
    if (tid < BW) hist[tid] = 0;
    for (int i = tid; i < len; i += 256) buf[i] = ebuf[beg + i];
    __syncthreads();
    for (int i = tid; i < len; i += 256)
        atomicAdd(&hist[buf[i] >> SRC_BITS], 1);
    __syncthreads();
    if (tid < BW) off[tid] = hist[tid];
    __syncthreads();
    for (int d = 1; d < BW; d <<= 1) {           // Hillis-Steele inclusive scan
        int v = (tid < BW && tid >= d) ? off[tid - d] : 0;
        __syncthreads();
        if (tid < BW) off[tid] += v;
        __syncthreads();
    }
    if (tid < BW) {
        int excl = off[tid] - hist[tid];
        int n = b * BW + tid;
        if (n < N) {
            rowptr[n] = beg + excl;
            dinv[n] = rsqrtf((float)(hist[tid] + 1));   // +1 self loop
        }
        cur[tid] = excl;
    }
    __syncthreads();
    for (int i = tid; i < len; i += 256) {
        int w = buf[i];
        int r = atomicAdd(&cur[w >> SRC_BITS], 1);
        ebuf[beg + r] = w & SRC_MASK;                   // store bare src
    }
}

// ---------- layer 1 GEMM: h0s[v] = (x[v] @ W1) * dinv[v] ----------
__global__ void k_gemm1(const float* __restrict__ x, const float* __restrict__ W1,
                        const float* __restrict__ dinv, float* __restrict__ h0s, int N) {
    int v = blockIdx.x * 256 + threadIdx.x;
    if (v >= N) return;
    const float4* xr = (const float4*)(x + (size_t)v * F);
    float acc[H];
    #pragma unroll
    for (int j = 0; j < H; j++) acc[j] = 0.f;
    for (int k4 = 0; k4 < F / 4; k4++) {
        float4 xv = xr[k4];
        const float* w = W1 + k4 * 4 * H;   // wave-uniform -> scalar loads
        #pragma unroll
        for (int j = 0; j < H; j++) acc[j] = fmaf(xv.x, w[j], acc[j]);
        #pragma unroll
        for (int j = 0; j < H; j++) acc[j] = fmaf(xv.y, w[H + j], acc[j]);
        #pragma unroll
        for (int j = 0; j < H; j++) acc[j] = fmaf(xv.z, w[2 * H + j], acc[j]);
        #pragma unroll
        for (int j = 0; j < H; j++) acc[j] = fmaf(xv.w, w[3 * H + j], acc[j]);
    }
    float dv = dinv[v];
    float4* o4 = (float4*)(h0s + (size_t)v * H);
    o4[0] = make_float4(acc[0] * dv, acc[1] * dv, acc[2] * dv, acc[3] * dv);
    o4[1] = make_float4(acc[4] * dv, acc[5] * dv, acc[6] * dv, acc[7] * dv);
    o4[2] = make_float4(acc[8] * dv, acc[9] * dv, acc[10] * dv, acc[11] * dv);
    o4[3] = make_float4(acc[12] * dv, acc[13] * dv, acc[14] * dv, acc[15] * dv);
}

// ---------- CSR node-parallel aggregation: 4 lanes/node, float4 gathers ----------
// relu_mode=1: out = relu(dinv*(acc) + b1[j]) * dinv   (layer-1, pre-scaled for layer 2)
// relu_mode=0: out = dinv*(acc)                        (layer-2, pre-W2)
__global__ void k_agg(const float* __restrict__ hs, const int* __restrict__ adj,
                      const int* __restrict__ rowptr, const float* __restrict__ dinv,
                      const float* __restrict__ b1, float* __restrict__ out,
                      int N, int relu_mode) {
    int t = blockIdx.x * 256 + threadIdx.x;
    int n = t >> 2, q = t & 3;
    if (n >= N) return;
    const float4* hs4 = (const float4*)hs;
    int beg = rowptr[n], end = rowptr[n + 1];
    float4 a = hs4[(size_t)n * 4 + q];   // self loop (already dinv[src]-scaled)
    float ax = a.x, ay = a.y, az = a.z, aw = a.w;
    int e = beg;
    for (; e + 3 < end; e += 4) {
        int s0 = adj[e], s1 = adj[e + 1], s2 = adj[e + 2], s3 = adj[e + 3];
        float4 v0 = hs4[(size_t)s0 * 4 + q];
        float4 v1 = hs4[(size_t)s1 * 4 + q];
        float4 v2 = hs4[(size_t)s2 * 4 + q];
        float4 v3 = hs4[(size_t)s3 * 4 + q];
        ax += (v0.x + v1.x) + (v2.x + v3.x);
        ay += (v0.y + v1.y) + (v2.y + v3.y);
        az += (v0.z + v1.z) + (v2.z + v3.z);
        aw += (v0.w + v1.w) + (v2.w + v3.w);
    }
    for (; e < end; e++) {
        int s = adj[e];
        float4 v = hs4[(size_t)s * 4 + q];
        ax += v.x; ay += v.y; az += v.z; aw += v.w;
    }
    float dv = dinv[n];
    float4 r;
    if (relu_mode) {
        r.x = fmaxf(fmaf(dv, ax, b1[q * 4 + 0]), 0.f) * dv;
        r.y = fmaxf(fmaf(dv, ay, b1[q * 4 + 1]), 0.f) * dv;
        r.z = fmaxf(fmaf(dv, az, b1[q * 4 + 2]), 0.f) * dv;
        r.w = fmaxf(fmaf(dv, aw, b1[q * 4 + 3]), 0.f) * dv;
    } else {
        r.x = dv * ax; r.y = dv * ay; r.z = dv * az; r.w = dv * aw;
    }
    ((float4*)out)[(size_t)n * 4 + q] = r;
}

// ---------- epilogue: h2 = g2 @ W2 + b2 ; softmax ; one wave per node ----------
__global__ void k_out(const float* __restrict__ g2, const float* __restrict__ W2,
                      const float* __restrict__ b2, float* __restrict__ dout, int N) {
    int t = blockIdx.x * 256 + threadIdx.x;
    int n = t >> 6, lane = t & 63;
    if (n >= N) return;
    const float* g = g2 + (size_t)n * H;
    float acc = 0.f;
    #pragma unroll
    for (int k = 0; k < H; k++) {
        float w = (lane < C) ? W2[k * C + lane] : 0.f;
        acc = fmaf(g[k], w, acc);
    }
    float h2 = (lane < C) ? acc + b2[lane] : -INFINITY;
    float m = h2;
    #pragma unroll
    for (int off = 32; off; off >>= 1) m = fmaxf(m, __shfl_xor(m, off, 64));
    float ex = (lane < C) ? __expf(h2 - m) : 0.f;
    float s = ex;
    #pragma unroll
    for (int off = 32; off; off >>= 1) s += __shfl_xor(s, off, 64);
    if (lane < C) {
        float inv = 1.f / s;
        dout[(size_t)n * C + lane] = ex * inv;                       // output 0: softmax
        dout[(size_t)N * C + (size_t)n * C + lane] = h2;             // output 1: logits
    }
}

extern "C" void kernel_launch(void* const* d_in, const int* in_sizes, int n_in,
                              void* d_out, int out_size, void* d_ws, size_t ws_size,
                              hipStream_t stream) {
    const float* x  = (const float*)d_in[0];
    const int*   ei = (const int*)d_in[1];
    const float* W1 = (const float*)d_in[3];
    const float* b1 = (const float*)d_in[4];
    const float* W2 = (const float*)d_in[5];
    const float* b2 = (const float*)d_in[6];
    float* out = (float*)d_out;

    int N = in_sizes[0] / F;       // 100000
    int E = in_sizes[1] / 2;       // 3200000
    const int* src = ei;
    const int* dst = ei + E;
    int NB = (N + BW - 1) / BW;    // 782 (<= NB_MAX)

    // workspace layout
    float* ws = (float*)d_ws;
    size_t o = 0;
    int* gbh    = (int*)(ws + o); o += (size_t)NB_MAX;
    int* brow   = (int*)(ws + o); o += (size_t)NB_MAX + 4;
    int* bcur   = (int*)(ws + o); o += (size_t)NB_MAX;
    int* rowptr = (int*)(ws + o); o += (size_t)N + 4;
    int* ebuf   = (int*)(ws + o); o += (size_t)E;
    float* dinv = ws + o;         o += (size_t)N;
    float* h0s  = ws + o;         o += (size_t)N * H;
    float* h1s  = ws + o;         o += (size_t)N * H;
    float* g2   = ws + o;         o += (size_t)N * H;

    int nb  = (N + 255) / 256;
    int nch = (E + CHUNK - 1) / CHUNK;   // 782

    hipMemsetAsync(gbh, 0, (size_t)NB_MAX * sizeof(int), stream);
    k_bhist   <<<nch, 256, 0, stream>>>(dst, gbh, E, NB);
    k_bscan   <<<1, 1024, 0, stream>>>(gbh, brow, bcur, rowptr, NB, N, E);
    k_bscatter<<<nch, 256, 0, stream>>>(src, dst, bcur, ebuf, E, NB);
    k_sortb   <<<NB, 256, 0, stream>>>(ebuf, brow, rowptr, dinv, N);
    k_gemm1   <<<nb, 256, 0, stream>>>(x, W1, dinv, h0s, N);
    k_agg     <<<(N * 4 + 255) / 256, 256, 0, stream>>>(h0s, ebuf, rowptr, dinv, b1, h1s, N, 1);
    k_agg     <<<(N * 4 + 255) / 256, 256, 0, stream>>>(h1s, ebuf, rowptr, dinv, b1, g2, N, 0);
    k_out     <<<(N * 64 + 255) / 256, 256, 0, stream>>>(g2, W2, b2, out, N);
}